// Round 1
// baseline (253.152 us; speedup 1.0000x reference)
//
#include <hip/hip_runtime.h>
#include <hip/hip_bf16.h>

#define B_ 4096
#define D_ 1024
#define H_ 8192
#define O_ 1000

#define BM 128
#define BN 128
#define BK 64

typedef __attribute__((ext_vector_type(8))) short short8;
typedef __attribute__((ext_vector_type(4))) short short4v;
typedef __attribute__((ext_vector_type(4))) float f32x4;

union BF4 { __hip_bfloat16 b[4]; short4v s; };

// ---------------- split fp32 -> bf16 hi/lo (pre-swizzled) + row sum-of-squares ----------
// Global layout of hi/lo: within each 64-elem (128B) chunk of a row, 16B unit u
// stores logical unit u ^ (row & 7).  GEMM stages these rows linearly into LDS
// and applies the same XOR on ds_read -> ~conflict-free b128 reads.
__global__ __launch_bounds__(256) void split_rows_kernel(
    const float* __restrict__ src,
    __hip_bfloat16* __restrict__ hi,
    __hip_bfloat16* __restrict__ lo,
    float* __restrict__ sq)
{
  const int row = blockIdx.x;
  const int t = threadIdx.x;
  const float4 v = ((const float4*)(src + (size_t)row * D_))[t];

  float ss = v.x * v.x + v.y * v.y + v.z * v.z + v.w * v.w;

  BF4 Hh, Ll;
  const float e[4] = {v.x, v.y, v.z, v.w};
#pragma unroll
  for (int i = 0; i < 4; ++i) {
    __hip_bfloat16 h = __float2bfloat16(e[i]);
    float r = e[i] - __bfloat162float(h);
    Hh.b[i] = h;
    Ll.b[i] = __float2bfloat16(r);
  }
  // thread t owns logical elems [4t, 4t+4): chunk kb = t>>4, logical unit (t>>1)&7
  const int kb = t >> 4;
  const int u = ((t >> 1) & 7) ^ (row & 7);
  const int dst = kb * 64 + u * 8 + (t & 1) * 4;
  *(short4v*)(hi + (size_t)row * D_ + dst) = Hh.s;
  *(short4v*)(lo + (size_t)row * D_ + dst) = Ll.s;

#pragma unroll
  for (int off = 32; off > 0; off >>= 1) ss += __shfl_down(ss, off);
  __shared__ float wsum[4];
  if ((t & 63) == 0) wsum[t >> 6] = ss;
  __syncthreads();
  if (t == 0) sq[row] = (wsum[0] + wsum[1]) + (wsum[2] + wsum[3]);
}

// ---------------- GEMM (bf16x3) + fused argmin ----------------
__device__ __forceinline__ void gload16(void* lds, const void* g) {
  __builtin_amdgcn_global_load_lds(
      (const __attribute__((address_space(1))) unsigned int*)g,
      (__attribute__((address_space(3))) unsigned int*)lds, 16, 0, 0);
}

#define MFMA_BF16 __builtin_amdgcn_mfma_f32_16x16x32_bf16

__global__ __launch_bounds__(256, 2) void gemm_argmin_kernel(
    const __hip_bfloat16* __restrict__ xh, const __hip_bfloat16* __restrict__ xl,
    const __hip_bfloat16* __restrict__ wh, const __hip_bfloat16* __restrict__ wl,
    const float* __restrict__ xsq, const float* __restrict__ wsq,
    unsigned long long* __restrict__ keys)
{
  __shared__ __hip_bfloat16 sAh[BM * BK], sAl[BM * BK];
  __shared__ __hip_bfloat16 sBh[BN * BK], sBl[BN * BK];

  const int t = threadIdx.x;
  const int brow = blockIdx.y * BM;
  const int bcol = blockIdx.x * BN;

  const int lane = t & 63;
  const int wid = t >> 6;
  const int wr = (wid >> 1) * 64;  // wave's row offset in tile
  const int wc = (wid & 1) * 64;   // wave's col offset in tile

  const int trow = t >> 3;       // staging row 0..31
  const int tu8 = (t & 7) * 8;   // staging unit offset (elems)

  const __hip_bfloat16* gAh = xh + (size_t)(brow + trow) * D_ + tu8;
  const __hip_bfloat16* gAl = xl + (size_t)(brow + trow) * D_ + tu8;
  const __hip_bfloat16* gBh = wh + (size_t)(bcol + trow) * D_ + tu8;
  const __hip_bfloat16* gBl = wl + (size_t)(bcol + trow) * D_ + tu8;

  f32x4 acc[4][4] = {};

  const int cc = lane & 15;
  const int q = lane >> 4;
  const int swz = lane & 7;  // == row&7 and col&7 for fragment rows/cols

  for (int kt = 0; kt < D_ / BK; ++kt) {
    const int ko = kt * BK;
#pragma unroll
    for (int p = 0; p < 4; ++p) {
      const size_t go = (size_t)p * 32 * D_ + ko;
      gload16(sAh + t * 8 + p * 2048, gAh + go);
      gload16(sAl + t * 8 + p * 2048, gAl + go);
      gload16(sBh + t * 8 + p * 2048, gBh + go);
      gload16(sBl + t * 8 + p * 2048, gBl + go);
    }
    __syncthreads();

#pragma unroll
    for (int kk = 0; kk < 2; ++kk) {
      short8 ah[4], al[4], bh[4], bl[4];
      const int uu = ((kk * 4 + q) ^ swz) * 8;
#pragma unroll
      for (int m = 0; m < 4; ++m) {
        const int off = (wr + m * 16 + cc) * BK + uu;
        ah[m] = *(const short8*)(sAh + off);
        al[m] = *(const short8*)(sAl + off);
      }
#pragma unroll
      for (int n = 0; n < 4; ++n) {
        const int off = (wc + n * 16 + cc) * BK + uu;
        bh[n] = *(const short8*)(sBh + off);
        bl[n] = *(const short8*)(sBl + off);
      }
#pragma unroll
      for (int m = 0; m < 4; ++m)
#pragma unroll
        for (int n = 0; n < 4; ++n) {
          acc[m][n] = MFMA_BF16(ah[m], bh[n], acc[m][n], 0, 0, 0);
          acc[m][n] = MFMA_BF16(al[m], bh[n], acc[m][n], 0, 0, 0);
          acc[m][n] = MFMA_BF16(ah[m], bl[n], acc[m][n], 0, 0, 0);
        }
    }
    __syncthreads();
  }

  // Epilogue: s = (x_sq - 2*acc) + w_sq  (replicates reference fp32 rounding order),
  // pack (orderable(s) << 32) | h  -> min = smallest score, ties -> smallest h.
  // D-frag layout (16x16x32): col = lane&15, row = (lane>>4)*4 + reg.
#pragma unroll
  for (int m = 0; m < 4; ++m) {
#pragma unroll
    for (int r = 0; r < 4; ++r) {
      const int row = brow + wr + m * 16 + q * 4 + r;
      const float xs = xsq[row];
      unsigned long long best = ~0ULL;
#pragma unroll
      for (int n = 0; n < 4; ++n) {
        const int col = bcol + wc + n * 16 + cc;
        const float s = (xs - 2.0f * acc[m][n][r]) + wsq[col];
        unsigned ub = __float_as_uint(s);
        ub = (ub & 0x80000000u) ? ~ub : (ub | 0x80000000u);
        const unsigned long long key =
            ((unsigned long long)ub << 32) | (unsigned)col;
        if (key < best) best = key;
      }
#pragma unroll
      for (int off2 = 1; off2 < 16; off2 <<= 1) {
        const unsigned long long o = __shfl_xor(best, off2);
        if (o < best) best = o;
      }
      if (cc == 0) atomicMin(&keys[row], best);
    }
  }
}

// ---------------- transpose G [O,H] -> GT [H,O] ----------------
__global__ __launch_bounds__(256) void transposeG_kernel(
    const float* __restrict__ G, float* __restrict__ GT)
{
  __shared__ float tile[32][33];
  const int h0 = blockIdx.x * 32;
  const int o0 = blockIdx.y * 32;
  const int tx = threadIdx.x;
  const int ty = threadIdx.y;
#pragma unroll
  for (int j = 0; j < 4; ++j) {
    const int o = o0 + ty + j * 8;
    if (o < O_) tile[ty + j * 8][tx] = G[(size_t)o * H_ + h0 + tx];
  }
  __syncthreads();
  const int o = o0 + tx;
  if (o < O_) {
#pragma unroll
    for (int j = 0; j < 4; ++j) {
      GT[(size_t)(h0 + ty + j * 8) * O_ + o] = tile[tx][ty + j * 8];
    }
  }
}

// ---------------- winners + row gather ----------------
__global__ __launch_bounds__(256) void finalize_kernel(
    const unsigned long long* __restrict__ keys,
    const float* __restrict__ GT, float* __restrict__ out)
{
  const int b = blockIdx.x;
  const unsigned w = (unsigned)(keys[b] & 0xFFFFFFFFull);
  if (threadIdx.x == 0) out[(size_t)B_ * O_ + b] = (float)w;
  const float4* src = (const float4*)(GT + (size_t)w * O_);
  float4* dst = (float4*)(out + (size_t)b * O_);
  for (int i = threadIdx.x; i < O_ / 4; i += 256) dst[i] = src[i];
}

extern "C" void kernel_launch(void* const* d_in, const int* in_sizes, int n_in,
                              void* d_out, int out_size, void* d_ws, size_t ws_size,
                              hipStream_t stream)
{
  (void)in_sizes; (void)n_in; (void)out_size; (void)ws_size;
  const float* x = (const float*)d_in[0];
  const float* kw = (const float*)d_in[1];
  const float* gw = (const float*)d_in[2];
  float* out = (float*)d_out;

  char* ws = (char*)d_ws;
  // layout: xh 8.4MB | xl 8.4MB | wh 16.8MB | wl 16.8MB | xsq 16KB | wsq 32KB | keys 32KB
  __hip_bfloat16* xh = (__hip_bfloat16*)(ws);
  __hip_bfloat16* xl = (__hip_bfloat16*)(ws + 8388608);
  __hip_bfloat16* wh = (__hip_bfloat16*)(ws + 16777216);
  __hip_bfloat16* wl = (__hip_bfloat16*)(ws + 33554432);
  float* xsq = (float*)(ws + 50331648);
  float* wsq = (float*)(ws + 50331648 + 16384);
  unsigned long long* keys = (unsigned long long*)(ws + 50331648 + 16384 + 32768);
  float* GT = (float*)(ws + 16777216);  // reuses wh/wl space after the GEMM is done

  hipMemsetAsync(keys, 0xFF, B_ * sizeof(unsigned long long), stream);
  split_rows_kernel<<<B_, 256, 0, stream>>>(x, xh, xl, xsq);
  split_rows_kernel<<<H_, 256, 0, stream>>>(kw, wh, wl, wsq);
  gemm_argmin_kernel<<<dim3(H_ / BN, B_ / BM), 256, 0, stream>>>(
      xh, xl, wh, wl, xsq, wsq, keys);
  transposeG_kernel<<<dim3(H_ / 32, (O_ + 31) / 32), dim3(32, 8), 0, stream>>>(gw, GT);
  finalize_kernel<<<B_, 256, 0, stream>>>(keys, GT, out);
}